// Round 2
// baseline (2092.309 us; speedup 1.0000x reference)
//
#include <hip/hip_runtime.h>

#define NC 128      // channels
#define NB 8        // batch

// ---------------------------------------------------------------------------
// LL-only Haar downsample: P (NB, 2h, 2w, NC) -> out (NB, h, w, NC)
// float4 over channels (16B/lane loads, fully coalesced)
// ---------------------------------------------------------------------------
__global__ __launch_bounds__(256) void k_haar_ll(
    const float* __restrict__ P, float* __restrict__ out, int h, int w)
{
    int idx = blockIdx.x * blockDim.x + threadIdx.x;
    int total = NB * h * w * (NC / 4);
    if (idx >= total) return;
    int cq = idx & (NC / 4 - 1);
    int t  = idx / (NC / 4);
    int j  = t % w; t /= w;
    int i  = t % h;
    int b  = t / h;
    size_t W2C  = (size_t)(2 * w) * NC;
    size_t base = (((size_t)b * (2 * h) + 2 * i) * (2 * w) + 2 * j) * NC + cq * 4;
    float4 A  = *(const float4*)(P + base);
    float4 Bv = *(const float4*)(P + base + NC);
    float4 Cv = *(const float4*)(P + base + W2C);
    float4 Dv = *(const float4*)(P + base + W2C + NC);
    float4 r;
    r.x = (A.x + Bv.x + Cv.x + Dv.x) * 0.5f;
    r.y = (A.y + Bv.y + Cv.y + Dv.y) * 0.5f;
    r.z = (A.z + Bv.z + Cv.z + Dv.z) * 0.5f;
    r.w = (A.w + Bv.w + Cv.w + Dv.w) * 0.5f;
    *(float4*)(out + (size_t)idx * 4) = r;
}

// ---------------------------------------------------------------------------
// Fused: depthwise-conv on on-the-fly Haar subbands of P, add next_ll to LL,
// Haar inverse, write 4 output pixels. Optionally fuse the base depthwise
// path (level 0 only).
//   P   : (NB, 2h, 2w, NC)  parent plane (x / ll0 / ll1)
//   nll : (NB, h, w, NC) or nullptr
//   wk  : (5,5,1,4*NC) level kernel, wsc: (4*NC) level scale
//   out : (NB, 2h, 2w, NC)
// Dynamic LDS: wl[4][25][NC] (0.5*scale*kernel), then if BASE: wb[25][NC],
// bscale[NC], bbias[NC].
// blockDim = (128, 2). Grid = (ceil(w/jt), h, NB).
// ---------------------------------------------------------------------------
template <bool BASE>
__global__ __launch_bounds__(256) void k_convinv(
    const float* __restrict__ P, const float* __restrict__ nll,
    const float* __restrict__ wk, const float* __restrict__ wsc,
    const float* __restrict__ bk, const float* __restrict__ bb,
    const float* __restrict__ bs, float* __restrict__ out,
    int h, int w, int jt)
{
    extern __shared__ float lds[];
    float* wl = lds;                       // 4*25*NC
    float* wbase = wl + 4 * 25 * NC;       // 25*NC (BASE)
    float* bscale = wbase + 25 * NC;       // NC (BASE)
    float* bbias  = bscale + NC;           // NC (BASE)

    int tid = threadIdx.x + threadIdx.y * blockDim.x;  // 0..255
    for (int u = tid; u < 4 * 25 * NC; u += 256) {
        int c  = u & (NC - 1);
        int st = u / NC;
        int t  = st % 25;
        int s  = st / 25;
        wl[u] = 0.5f * wsc[c * 4 + s] * wk[t * (4 * NC) + c * 4 + s];
    }
    if (BASE) {
        for (int u = tid; u < 25 * NC; u += 256) wbase[u] = bk[u];
        for (int u = tid; u < NC; u += 256) { bscale[u] = bs[u]; bbias[u] = bb[u]; }
    }
    __syncthreads();

    const int c  = threadIdx.x;    // channel lane
    const int ty = threadIdx.y;
    const int b  = blockIdx.z;
    const int i  = blockIdx.y;
    const int j0 = blockIdx.x * jt;
    const int PH = 2 * h, PW = 2 * w;
    const size_t rowC = (size_t)PW * NC;

    for (int jj = ty; jj < jt; jj += 2) {
        int j = j0 + jj;
        if (j >= w) break;

        float acc0 = 0.f, acc1 = 0.f, acc2 = 0.f, acc3 = 0.f;
        for (int ky = 0; ky < 5; ++ky) {
            int y = i + ky - 2;
            if (y < 0 || y >= h) continue;
            const float* prow = P + (((size_t)b * PH + 2 * y) * PW) * NC;
            for (int kx = 0; kx < 5; ++kx) {
                int xq = j + kx - 2;
                if (xq < 0 || xq >= w) continue;
                int t = ky * 5 + kx;
                const float* p = prow + (size_t)(2 * xq) * NC + c;
                float A  = p[0];
                float Bv = p[NC];
                float Cv = p[rowC];
                float Dv = p[rowC + NC];
                float sA = A + Bv, sC = Cv + Dv;
                float dA = A - Bv, dC = Cv - Dv;
                acc0 += (sA + sC) * wl[(0 * 25 + t) * NC + c];
                acc1 += (sA - sC) * wl[(1 * 25 + t) * NC + c];
                acc2 += (dA + dC) * wl[(2 * 25 + t) * NC + c];
                acc3 += (dA - dC) * wl[(3 * 25 + t) * NC + c];
            }
        }
        if (nll) acc0 += nll[(((size_t)b * h + i) * w + j) * NC + c];

        float av = (acc0 + acc1 + acc2 + acc3) * 0.5f;
        float bv = (acc0 + acc1 - acc2 - acc3) * 0.5f;
        float cv = (acc0 - acc1 + acc2 - acc3) * 0.5f;
        float dv = (acc0 - acc1 - acc2 + acc3) * 0.5f;

        size_t ob = (((size_t)b * PH + 2 * i) * PW + 2 * j) * NC + c;
        if (BASE) {
            float bacc00 = 0.f, bacc01 = 0.f, bacc10 = 0.f, bacc11 = 0.f;
            for (int pr = -2; pr <= 3; ++pr) {
                int px = 2 * i + pr;
                if (px < 0 || px >= PH) continue;
                const float* xrow = P + ((size_t)b * PH + px) * rowC;
                for (int pc = -2; pc <= 3; ++pc) {
                    int py = 2 * j + pc;
                    if (py < 0 || py >= PW) continue;
                    float v = xrow[(size_t)py * NC + c];
                    int ky0 = pr + 2, kx0 = pc + 2;   // tap for r=0 / u=0
                    if (ky0 <= 4 && kx0 <= 4)
                        bacc00 += v * wbase[(ky0 * 5 + kx0) * NC + c];
                    if (ky0 <= 4 && kx0 - 1 >= 0)
                        bacc01 += v * wbase[(ky0 * 5 + kx0 - 1) * NC + c];
                    if (ky0 - 1 >= 0 && kx0 <= 4)
                        bacc10 += v * wbase[((ky0 - 1) * 5 + kx0) * NC + c];
                    if (ky0 - 1 >= 0 && kx0 - 1 >= 0)
                        bacc11 += v * wbase[((ky0 - 1) * 5 + kx0 - 1) * NC + c];
                }
            }
            float sc = bscale[c], bi = bbias[c];
            out[ob]             = sc * (bacc00 + bi) + av;
            out[ob + NC]        = sc * (bacc01 + bi) + bv;
            out[ob + rowC]      = sc * (bacc10 + bi) + cv;
            out[ob + rowC + NC] = sc * (bacc11 + bi) + dv;
        } else {
            out[ob]             = av;
            out[ob + NC]        = bv;
            out[ob + rowC]      = cv;
            out[ob + rowC + NC] = dv;
        }
    }
}

// ---------------------------------------------------------------------------
extern "C" void kernel_launch(void* const* d_in, const int* in_sizes, int n_in,
                              void* d_out, int out_size, void* d_ws, size_t ws_size,
                              hipStream_t stream)
{
    const float* x  = (const float*)d_in[0];
    const float* bk = (const float*)d_in[1];
    const float* bb = (const float*)d_in[2];
    const float* bs = (const float*)d_in[3];
    const float* wk[3];
    const float* wv[3];
    if (n_in >= 10) {
        // tuples flattened into separate pointers
        for (int i = 0; i < 3; ++i) {
            wk[i] = (const float*)d_in[4 + i];
            wv[i] = (const float*)d_in[7 + i];
        }
    } else {
        // tuples concatenated into single buffers
        const float* wkc = (const float*)d_in[4];
        const float* wvc = (const float*)d_in[5];
        for (int i = 0; i < 3; ++i) {
            wk[i] = wkc + (size_t)i * 25 * 4 * NC;   // 12800 floats each
            wv[i] = wvc + (size_t)i * 4 * NC;        // 512 floats each
        }
    }
    float* out = (float*)d_out;

    // Intermediates whose lifetime ends BEFORE the final pass live inside
    // d_out (fully rewritten by the final kernel -> deterministic).
    float* ll0 = out;                       // (8,128,128,128) = 16,777,216 f
    float* ll1 = out + 16777216;            // (8, 64, 64,128) =  4,194,304 f
    float* r2  = out + 16777216 + 4194304;  // (8, 64, 64,128) =  4,194,304 f
    // r1 is read while the final kernel writes d_out -> must be in d_ws.
    float* r1  = (float*)d_ws;              // (8,128,128,128) = 64 MiB

    // 1) x -> ll0
    {
        int total = NB * 128 * 128 * (NC / 4);
        k_haar_ll<<<(total + 255) / 256, 256, 0, stream>>>(x, ll0, 128, 128);
    }
    // 2) ll0 -> ll1
    {
        int total = NB * 64 * 64 * (NC / 4);
        k_haar_ll<<<(total + 255) / 256, 256, 0, stream>>>(ll0, ll1, 64, 64);
    }

    size_t lds_nb = (size_t)(4 * 25 * NC) * sizeof(float);                     // 51200 B
    size_t lds_b  = (size_t)(4 * 25 * NC + 25 * NC + 2 * NC) * sizeof(float);  // 65024 B
    dim3 blk(128, 2);

    // 3) level 2: ll1 -> r2   (coeff grid 32x32)
    k_convinv<false><<<dim3(2, 32, NB), blk, lds_nb, stream>>>(
        ll1, nullptr, wk[2], wv[2], nullptr, nullptr, nullptr, r2, 32, 32, 16);

    // 4) level 1: ll0 (+r2) -> r1   (coeff grid 64x64)
    k_convinv<false><<<dim3(2, 64, NB), blk, lds_nb, stream>>>(
        ll0, r2, wk[1], wv[1], nullptr, nullptr, nullptr, r1, 64, 64, 32);

    // 5) level 0: x (+r1) + base path -> d_out   (coeff grid 128x128)
    k_convinv<true><<<dim3(4, 128, NB), blk, lds_b, stream>>>(
        x, r1, wk[0], wv[0], bk, bb, bs, out, 128, 128, 32);
}

// Round 3
// 759.611 us; speedup vs baseline: 2.7544x; 2.7544x over previous
//
#include <hip/hip_runtime.h>

#define NC 128      // channels
#define NB 8        // batch
#define CPB 32      // channels per block
#define JT 16       // j-tile width per block

// ---------------------------------------------------------------------------
// LL-only Haar downsample: P (NB, 2h, 2w, NC) -> out (NB, h, w, NC)
// ---------------------------------------------------------------------------
__global__ __launch_bounds__(256) void k_haar_ll(
    const float* __restrict__ P, float* __restrict__ out, int h, int w)
{
    int idx = blockIdx.x * blockDim.x + threadIdx.x;
    int total = NB * h * w * (NC / 4);
    if (idx >= total) return;
    int cq = idx & (NC / 4 - 1);
    int t  = idx / (NC / 4);
    int j  = t % w; t /= w;
    int i  = t % h;
    int b  = t / h;
    size_t W2C  = (size_t)(2 * w) * NC;
    size_t base = (((size_t)b * (2 * h) + 2 * i) * (2 * w) + 2 * j) * NC + cq * 4;
    float4 A  = *(const float4*)(P + base);
    float4 Bv = *(const float4*)(P + base + NC);
    float4 Cv = *(const float4*)(P + base + W2C);
    float4 Dv = *(const float4*)(P + base + W2C + NC);
    float4 r;
    r.x = (A.x + Bv.x + Cv.x + Dv.x) * 0.5f;
    r.y = (A.y + Bv.y + Cv.y + Dv.y) * 0.5f;
    r.z = (A.z + Bv.z + Cv.z + Dv.z) * 0.5f;
    r.w = (A.w + Bv.w + Cv.w + Dv.w) * 0.5f;
    *(float4*)(out + (size_t)idx * 4) = r;
}

// ---------------------------------------------------------------------------
// Fused conv-on-haar-subbands + inverse. 32 channels per block (low LDS ->
// high occupancy). BASE path fused into the tap loop: base-window x values
// are a subset of the A/B/C/D tap loads (ky,kx in {1,2,3}).
// blockDim = (32, 8). grid = ((w/JT)*4, h, NB). blockIdx.x = jtile*4 + cg.
// ---------------------------------------------------------------------------
template <bool BASE>
__global__ __launch_bounds__(256) void k_convinv(
    const float* __restrict__ P, const float* __restrict__ nll,
    const float* __restrict__ wk, const float* __restrict__ wsc,
    const float* __restrict__ bk, const float* __restrict__ bb,
    const float* __restrict__ bs, float* __restrict__ out,
    int h, int w)
{
    extern __shared__ float lds[];
    float* wl     = lds;               // [4][25][CPB]
    float* wbase  = wl + 4 * 25 * CPB; // [25][CPB]   (BASE)
    float* bscale = wbase + 25 * CPB;  // [CPB]       (BASE)
    float* bbias  = bscale + CPB;      // [CPB]       (BASE)

    const int cg    = blockIdx.x & 3;
    const int jtile = blockIdx.x >> 2;
    const int c0    = cg * CPB;
    const int tid   = threadIdx.x + threadIdx.y * 32;

    for (int u = tid; u < 4 * 25 * CPB; u += 256) {
        int tc = u & (CPB - 1);
        int st = u / CPB;
        int t  = st % 25;
        int s  = st / 25;
        wl[u] = 0.5f * wsc[(c0 + tc) * 4 + s] * wk[t * (4 * NC) + (c0 + tc) * 4 + s];
    }
    if (BASE) {
        for (int u = tid; u < 25 * CPB; u += 256) {
            int tc = u & (CPB - 1);
            int t  = u / CPB;
            wbase[u] = bk[t * NC + c0 + tc];
        }
        if (tid < CPB) { bscale[tid] = bs[c0 + tid]; bbias[tid] = bb[c0 + tid]; }
    }
    __syncthreads();

    const int tc = threadIdx.x;
    const int c  = c0 + tc;
    const int b  = blockIdx.z;
    const int i  = blockIdx.y;
    const int j0 = jtile * JT;
    const int PH = 2 * h, PW = 2 * w;
    const size_t rowC = (size_t)PW * NC;

    for (int jj = threadIdx.y; jj < JT; jj += 8) {
        int j = j0 + jj;

        float acc0 = 0.f, acc1 = 0.f, acc2 = 0.f, acc3 = 0.f;
        float b00 = 0.f, b01 = 0.f, b10 = 0.f, b11 = 0.f;

        #pragma unroll
        for (int ky = 0; ky < 5; ++ky) {
            int y = i + ky - 2;
            if (y < 0 || y >= h) continue;
            const float* prow = P + ((size_t)b * PH + 2 * y) * rowC + c;
            #pragma unroll
            for (int kx = 0; kx < 5; ++kx) {
                int xq = j + kx - 2;
                if (xq < 0 || xq >= w) continue;
                const int t = ky * 5 + kx;
                const float* p = prow + (size_t)(2 * xq) * NC;
                float A  = p[0];
                float Bv = p[NC];
                float Cv = p[rowC];
                float Dv = p[rowC + NC];
                float sA = A + Bv, sC = Cv + Dv;
                float dA = A - Bv, dC = Cv - Dv;
                acc0 += (sA + sC) * wl[(0 * 25 + t) * CPB + tc];
                acc1 += (sA - sC) * wl[(1 * 25 + t) * CPB + tc];
                acc2 += (dA + dC) * wl[(2 * 25 + t) * CPB + tc];
                acc3 += (dA - dC) * wl[(3 * 25 + t) * CPB + tc];
                if (BASE && ky >= 1 && ky <= 3 && kx >= 1 && kx <= 3) {
                    // Base conv fused on the already-loaded A/B/C/D values.
                    // Weight index map derived from row/col offsets (see notes):
                    //   A row m: 2ky-2 (out row 2i), 2ky-3 (out row 2i+1, ky>=2)
                    //   C row m: 2ky-1 (out row 2i, ky<=2), 2ky-2 (out row 2i+1)
                    //   A col n: 2kx-2 (out col 2j), 2kx-3 (out col 2j+1, kx>=2)
                    //   B col n: 2kx-1 (out col 2j, kx<=2), 2kx-2 (out col 2j+1)
                    b00 += A  * wbase[((2*ky-2) * 5 + (2*kx-2)) * CPB + tc];
                    if (kx >= 2)            b01 += A  * wbase[((2*ky-2) * 5 + (2*kx-3)) * CPB + tc];
                    if (ky >= 2)            b10 += A  * wbase[((2*ky-3) * 5 + (2*kx-2)) * CPB + tc];
                    if (ky >= 2 && kx >= 2) b11 += A  * wbase[((2*ky-3) * 5 + (2*kx-3)) * CPB + tc];
                    if (kx <= 2)            b00 += Bv * wbase[((2*ky-2) * 5 + (2*kx-1)) * CPB + tc];
                                            b01 += Bv * wbase[((2*ky-2) * 5 + (2*kx-2)) * CPB + tc];
                    if (ky >= 2 && kx <= 2) b10 += Bv * wbase[((2*ky-3) * 5 + (2*kx-1)) * CPB + tc];
                    if (ky >= 2)            b11 += Bv * wbase[((2*ky-3) * 5 + (2*kx-2)) * CPB + tc];
                    if (ky <= 2)            b00 += Cv * wbase[((2*ky-1) * 5 + (2*kx-2)) * CPB + tc];
                    if (ky <= 2 && kx >= 2) b01 += Cv * wbase[((2*ky-1) * 5 + (2*kx-3)) * CPB + tc];
                                            b10 += Cv * wbase[((2*ky-2) * 5 + (2*kx-2)) * CPB + tc];
                    if (kx >= 2)            b11 += Cv * wbase[((2*ky-2) * 5 + (2*kx-3)) * CPB + tc];
                    if (ky <= 2 && kx <= 2) b00 += Dv * wbase[((2*ky-1) * 5 + (2*kx-1)) * CPB + tc];
                    if (ky <= 2)            b01 += Dv * wbase[((2*ky-1) * 5 + (2*kx-2)) * CPB + tc];
                    if (kx <= 2)            b10 += Dv * wbase[((2*ky-2) * 5 + (2*kx-1)) * CPB + tc];
                                            b11 += Dv * wbase[((2*ky-2) * 5 + (2*kx-2)) * CPB + tc];
                }
            }
        }
        if (nll) acc0 += nll[(((size_t)b * h + i) * w + j) * NC + c];

        float av = (acc0 + acc1 + acc2 + acc3) * 0.5f;
        float bv = (acc0 + acc1 - acc2 - acc3) * 0.5f;
        float cv = (acc0 - acc1 + acc2 - acc3) * 0.5f;
        float dv = (acc0 - acc1 - acc2 + acc3) * 0.5f;

        size_t ob = ((size_t)b * PH + 2 * i) * rowC + (size_t)(2 * j) * NC + c;
        if (BASE) {
            float sc = bscale[tc], bi = bbias[tc];
            out[ob]             = sc * (b00 + bi) + av;
            out[ob + NC]        = sc * (b01 + bi) + bv;
            out[ob + rowC]      = sc * (b10 + bi) + cv;
            out[ob + rowC + NC] = sc * (b11 + bi) + dv;
        } else {
            out[ob]             = av;
            out[ob + NC]        = bv;
            out[ob + rowC]      = cv;
            out[ob + rowC + NC] = dv;
        }
    }
}

// ---------------------------------------------------------------------------
extern "C" void kernel_launch(void* const* d_in, const int* in_sizes, int n_in,
                              void* d_out, int out_size, void* d_ws, size_t ws_size,
                              hipStream_t stream)
{
    const float* x  = (const float*)d_in[0];
    const float* bk = (const float*)d_in[1];
    const float* bb = (const float*)d_in[2];
    const float* bs = (const float*)d_in[3];
    const float* wk[3];
    const float* wv[3];
    if (n_in >= 10) {
        for (int i = 0; i < 3; ++i) {
            wk[i] = (const float*)d_in[4 + i];
            wv[i] = (const float*)d_in[7 + i];
        }
    } else {
        const float* wkc = (const float*)d_in[4];
        const float* wvc = (const float*)d_in[5];
        for (int i = 0; i < 3; ++i) {
            wk[i] = wkc + (size_t)i * 25 * 4 * NC;
            wv[i] = wvc + (size_t)i * 4 * NC;
        }
    }
    float* out = (float*)d_out;

    // Dead-before-final intermediates live inside d_out (fully rewritten by
    // the final kernel). r1 (read during final pass) lives in d_ws.
    float* ll0 = out;                       // (8,128,128,128)
    float* ll1 = out + 16777216;            // (8, 64, 64,128)
    float* r2  = out + 16777216 + 4194304;  // (8, 64, 64,128)
    float* r1  = (float*)d_ws;              // (8,128,128,128) = 64 MiB

    // 1) x -> ll0
    {
        int total = NB * 128 * 128 * (NC / 4);
        k_haar_ll<<<(total + 255) / 256, 256, 0, stream>>>(x, ll0, 128, 128);
    }
    // 2) ll0 -> ll1
    {
        int total = NB * 64 * 64 * (NC / 4);
        k_haar_ll<<<(total + 255) / 256, 256, 0, stream>>>(ll0, ll1, 64, 64);
    }

    size_t lds_nb = (size_t)(4 * 25 * CPB) * sizeof(float);                      // 12800 B
    size_t lds_b  = (size_t)(4 * 25 * CPB + 25 * CPB + 2 * CPB) * sizeof(float); // 16256 B
    dim3 blk(32, 8);

    // 3) level 2: ll1 -> r2   (coeff grid 32x32)
    k_convinv<false><<<dim3((32 / JT) * 4, 32, NB), blk, lds_nb, stream>>>(
        ll1, nullptr, wk[2], wv[2], nullptr, nullptr, nullptr, r2, 32, 32);

    // 4) level 1: ll0 (+r2) -> r1   (coeff grid 64x64)
    k_convinv<false><<<dim3((64 / JT) * 4, 64, NB), blk, lds_nb, stream>>>(
        ll0, r2, wk[1], wv[1], nullptr, nullptr, nullptr, r1, 64, 64);

    // 5) level 0: x (+r1) + base path -> d_out   (coeff grid 128x128)
    k_convinv<true><<<dim3((128 / JT) * 4, 128, NB), blk, lds_b, stream>>>(
        x, r1, wk[0], wv[0], bk, bb, bs, out, 128, 128);
}